// Round 2
// 229.375 us; speedup vs baseline: 1.2585x; 1.2585x over previous
//
#include <hip/hip_runtime.h>

// R9b: MFMA rewrite (compile fix of R9: cvt_pkrtz returns __fp16x2 -> bit_cast
// to int instead of assigning to _Float16x2).
// emb-lookup -> LSTM(64) over T=512 -> Dense(3) -> softmax.
// 128 blocks x 256 thr, G=4 sequences per block. Per step, each wave computes
// z[4 seqs, 16 units x 4 gates] = [h|x][4,96]_fp16 @ W[96,256]_fp16 with
// 12 x v_mfma_f32_16x16x32_f16 (K=96 folds Wk in -> no x-projection table,
// no build kernel, no workspace). A-operand rows replicated 4x via LDS
// broadcast reads (lane reads row (l&15)>>2): C-frag reg0 then gives every
// lane all 4 gates of one (seq=l>>4, unit=16w+(l&15)) cell in-register --
// no quad reduce, no DPP broadcast, no redistribute. c-state fp32 in 1 VGPR.
// h handed off as fp16 via LDS; x staged fp16 with 2-step prefetch (xA/xB
// regs, loop unrolled x2 so buffers are static). LDS hx[2][4][96]: 192B rows
// -> dword slots {0,16} mod 32 per row, 2-way (free) on broadcast A-reads.

#define VOCAB 50000
#define EMB 32
#define HID 64
#define NCLS 3
#define BATCH 512
#define TSEQ 512
#define FOURH 256
#define LOG2E 1.4426950408889634f
#define GSEQ 4
#define NBLK (BATCH / GSEQ)

typedef _Float16 half8 __attribute__((ext_vector_type(8)));
typedef float f32x4 __attribute__((ext_vector_type(4)));

#define MFMA16 __builtin_amdgcn_mfma_f32_16x16x32_f16
#define PKRTZ(a, b) __builtin_bit_cast(int, __builtin_amdgcn_cvt_pkrtz((a), (b)))

// One LSTM step. CUR = current hx buffer, TT = timestep, XW = float4 regs
// holding x(TT+1) (written to hx[NXT] now), XL = regs to load x(TT+2) into.
#define LSTM_STEP(CUR, TT, XW, XL)                                            \
    {                                                                         \
        const half8* ap = (const half8*)(hxc + (CUR) * 768 + abase);          \
        const half8 a0 = ap[0];                                               \
        const half8 a1 = ap[4];                                               \
        const half8 a2 = ap[8];                                               \
        if (li8) {                                                            \
            int2 st;                                                          \
            st.x = PKRTZ(XW.x, XW.y);                                         \
            st.y = PKRTZ(XW.z, XW.w);                                         \
            *(int2*)(hxc + ((CUR) ^ 1) * 768 + xwoff) = st;                   \
            const int tn2 = ((TT) + 2 < TSEQ) ? (TT) + 2 : TSEQ - 1;          \
            const int tk = toks[(w << 9) + tn2];                              \
            XL = *(const float4*)(emb + tk * EMB + (l << 2));                 \
        }                                                                     \
        f32x4 ac0, ac1, ac2, ac3;                                             \
        ac0 = MFMA16(a0, bfr[0][0], zz, 0, 0, 0);                             \
        ac1 = MFMA16(a0, bfr[1][0], zz, 0, 0, 0);                             \
        ac2 = MFMA16(a0, bfr[2][0], zz, 0, 0, 0);                             \
        ac3 = MFMA16(a0, bfr[3][0], zz, 0, 0, 0);                             \
        ac0 = MFMA16(a1, bfr[0][1], ac0, 0, 0, 0);                            \
        ac1 = MFMA16(a1, bfr[1][1], ac1, 0, 0, 0);                            \
        ac2 = MFMA16(a1, bfr[2][1], ac2, 0, 0, 0);                            \
        ac3 = MFMA16(a1, bfr[3][1], ac3, 0, 0, 0);                            \
        ac0 = MFMA16(a2, bfr[0][2], ac0, 0, 0, 0);                            \
        ac1 = MFMA16(a2, bfr[1][2], ac1, 0, 0, 0);                            \
        ac2 = MFMA16(a2, bfr[2][2], ac2, 0, 0, 0);                            \
        ac3 = MFMA16(a2, bfr[3][2], ac3, 0, 0, 0);                            \
        const float zi = ac0[0], zf = ac1[0], zg = ac2[0], zo = ac3[0];       \
        const float si = __builtin_amdgcn_rcpf(                               \
            1.0f + __builtin_amdgcn_exp2f(fmaf(zi, -LOG2E, bci)));            \
        const float sf = __builtin_amdgcn_rcpf(                               \
            1.0f + __builtin_amdgcn_exp2f(fmaf(zf, -LOG2E, bcf)));            \
        const float sg = __builtin_amdgcn_rcpf(                               \
            1.0f + __builtin_amdgcn_exp2f(fmaf(zg, -2.0f * LOG2E, bcg)));     \
        const float so = __builtin_amdgcn_rcpf(                               \
            1.0f + __builtin_amdgcn_exp2f(fmaf(zo, -LOG2E, bco)));            \
        const float gt = fmaf(2.0f, sg, -1.0f);                               \
        cst = fmaf(sf, cst, si * gt);                                         \
        const float st2 = __builtin_amdgcn_rcpf(                              \
            1.0f + __builtin_amdgcn_exp2f(cst * (-2.0f * LOG2E)));            \
        const float th = fmaf(2.0f, st2, -1.0f);                              \
        const float hv = so * th;                                             \
        *(_Float16*)(hxc + ((CUR) ^ 1) * 768 + hwoff) = (_Float16)hv;         \
        __syncthreads();                                                      \
    }

__global__ __launch_bounds__(256)
void lstm_kernel(const int* __restrict__ tokens, const float* __restrict__ emb,
                 const float* __restrict__ Wk, const float* __restrict__ Wr,
                 const float* __restrict__ bias, const float* __restrict__ Wd,
                 const float* __restrict__ bd, float* __restrict__ out)
{
    // [buf][seq][k]: k 0..63 = h (fp16), k 64..95 = x (fp16). Row = 192 B.
    __shared__ __align__(16) _Float16 hx[2][GSEQ][96];
    __shared__ int toks[GSEQ * TSEQ];

    const int tid = threadIdx.x;
    const int w   = tid >> 6;          // wave 0..3 -> unit slice [16w,16w+16)
    const int l   = tid & 63;
    const int li  = l & 15;
    const int q   = l >> 4;            // seq id for activation; k-subchunk for frags
    const bool li8 = (l < 8);
    const int s0  = blockIdx.x << 2;   // first sequence of this block

    char* hxc = (char*)&hx[0][0][0];

    // ---- stage all 2048 tokens (contiguous 8 KB) ----
    {
        const int4* src = (const int4*)(tokens + (s0 << 9));
        int4* dst = (int4*)toks;
        dst[tid] = src[tid];
        dst[tid + 256] = src[tid + 256];
    }

    // ---- zero h-region of buffer 0 (4 rows x 128 B) ----
    if (tid < 64) {
        int2 z2; z2.x = 0; z2.y = 0;
        *(int2*)(hxc + (tid >> 4) * 192 + ((tid & 15) << 3)) = z2;
    }

    // ---- persistent fp16 weight fragments: B[k, col], col = 64g + 16w + li,
    //      k = 32*c2 + 8*q + i.  Rows 0..63 = Wr, 64..95 = Wk. ----
    half8 bfr[4][3];
#pragma unroll
    for (int g = 0; g < 4; ++g) {
        const int col = (g << 6) + (w << 4) + li;
#pragma unroll
        for (int c2 = 0; c2 < 3; ++c2) {
#pragma unroll
            for (int i = 0; i < 8; ++i) {
                const int k = (c2 << 5) + (q << 3) + i;
                const float wv = (k < HID) ? Wr[k * FOURH + col]
                                           : Wk[(k - HID) * FOURH + col];
                bfr[g][c2][i] = (_Float16)wv;
            }
        }
    }

    // ---- activation constants (bias folded into exp2 argument) ----
    const int u = (w << 4) + li;
    const float bci = -bias[u] * LOG2E;
    const float bcf = -bias[u + 64] * LOG2E;
    const float bcg = -bias[u + 128] * (2.0f * LOG2E);
    const float bco = -bias[u + 192] * LOG2E;

    // ---- per-lane LDS byte offsets ----
    const int abase = ((li >> 2) * 192) + (q << 4);   // A-frag base (row bcast)
    const int hwoff = q * 192 + (u << 1);             // h write: [seq=q][u]
    const int xwoff = w * 192 + 128 + (l << 3);       // x write: [seq=w][64+4l..]

    __syncthreads();   // toks + zeroed h visible

    // ---- stage x(0) into buf0; preload xA = x(1) ----
    float4 xA = make_float4(0.f, 0.f, 0.f, 0.f);
    float4 xB = make_float4(0.f, 0.f, 0.f, 0.f);
    if (li8) {
        const int tk0 = toks[w << 9];
        const float4 x0 = *(const float4*)(emb + tk0 * EMB + (l << 2));
        int2 st;
        st.x = PKRTZ(x0.x, x0.y);
        st.y = PKRTZ(x0.z, x0.w);
        *(int2*)(hxc + xwoff) = st;
        const int tk1 = toks[(w << 9) + 1];
        xA = *(const float4*)(emb + tk1 * EMB + (l << 2));
    }
    __syncthreads();

    float cst = 0.0f;
    const f32x4 zz = {0.0f, 0.0f, 0.0f, 0.0f};

    for (int t = 0; t < TSEQ; t += 2) {
        LSTM_STEP(0, t, xA, xB)
        LSTM_STEP(1, t + 1, xB, xA)
    }

    // ---- epilogue: final h is in hx[0] (T even). Dense(3) + softmax. ----
    if (tid < GSEQ) {
        const _Float16* hf = &hx[0][tid][0];
        float a0 = bd[0], a1 = bd[1], a2 = bd[2];
#pragma unroll 8
        for (int k = 0; k < HID; ++k) {
            const float hk = (float)hf[k];
            a0 = fmaf(hk, Wd[k * NCLS + 0], a0);
            a1 = fmaf(hk, Wd[k * NCLS + 1], a1);
            a2 = fmaf(hk, Wd[k * NCLS + 2], a2);
        }
        const float mm = fmaxf(a0, fmaxf(a1, a2));
        const float e0 = __expf(a0 - mm);
        const float e1 = __expf(a1 - mm);
        const float e2 = __expf(a2 - mm);
        const float den = e0 + e1 + e2;
        float* op = out + (s0 + tid) * NCLS;
        op[0] = e0 / den;
        op[1] = e1 / den;
        op[2] = e2 / den;
    }
}

extern "C" void kernel_launch(void* const* d_in, const int* in_sizes, int n_in,
                              void* d_out, int out_size, void* d_ws, size_t ws_size,
                              hipStream_t stream) {
    const int*   tokens = (const int*)  d_in[0];
    const float* emb    = (const float*)d_in[1];
    const float* Wk     = (const float*)d_in[2];
    const float* Wr     = (const float*)d_in[3];
    const float* b      = (const float*)d_in[4];
    const float* Wd     = (const float*)d_in[5];
    const float* bd     = (const float*)d_in[6];
    float* out = (float*)d_out;
    (void)d_ws; (void)ws_size; (void)in_sizes; (void)n_in; (void)out_size;

    lstm_kernel<<<dim3(NBLK), dim3(256), 0, stream>>>(
        tokens, emb, Wk, Wr, b, Wd, bd, out);
}